// Round 12
// baseline (66.078 us; speedup 1.0000x reference)
//
#include <hip/hip_runtime.h>
#include <hip/hip_bf16.h>

#define T_TOTAL 200000
#define STEPF (999.0f / 199999.0f)

// Parameter block (floats), phases in REVOLUTIONS, +0.25-shifted so
// sin(theta) = cos(2*pi*(fract(rev)-0.5)) (even poly, no sign fixup):
// [0..79]      layer0 quads at 4n, n<20: {ww0', ph0'+0.25, A0, 0}
// [80..1079]   layer1 pairs at 80  + 2*(m*20+n): {ww1', ph1'+0.25}, m<25,n<20
// [1080..2579] layer2 pairs at 1080+ 2*(m*25+n): m<30, n<25
// [2580..2639] layer3 pairs at 2580+ 2*m: m<30
__device__ float g_P[2640];
// Inter-kernel s1 buffer: s1[m][t], m<25. 20 MB; written by A, read by B.
__device__ float g_s1[25 * T_TOTAL];

// sin(2*pi*rev) via even poly: cos(2*pi*h), h = fract(rev)-0.5. |err| ~= 4e-5.
__device__ __forceinline__ float sinp(float rev) {
    float g = __builtin_amdgcn_fractf(rev);
    float h = g - 0.5f;
    float u = h * h;
    float p = fmaf(45.621248f, u, -82.391040f);
    p = fmaf(p, u, 64.671616f);
    p = fmaf(p, u, -19.730960f);
    p = fmaf(p, u, 0.9999618f);
    return p;
}

__global__ void prep_kernel(
    const float* __restrict__ A0,
    const float* __restrict__ w0, const float* __restrict__ phi0,
    const float* __restrict__ wc0, const float* __restrict__ phic0,
    const float* __restrict__ w1, const float* __restrict__ phi1,
    const float* __restrict__ wc1, const float* __restrict__ phic1,
    const float* __restrict__ w2, const float* __restrict__ phi2,
    const float* __restrict__ wc2, const float* __restrict__ phic2,
    const float* __restrict__ w3, const float* __restrict__ phi3,
    const float* __restrict__ wc3, const float* __restrict__ phic3)
{
    const int tid = blockIdx.x * blockDim.x + threadIdx.x;
    const int stride = blockDim.x * gridDim.x;

    const double I2PI = 0.15915494309189535;

    const double ws0 = fmax((double)wc0[0], 0.0), ps0 = fmax((double)phic0[0], 0.0);
    const double ws1 = fmax((double)wc1[0], 0.0), ps1 = fmax((double)phic1[0], 0.0);
    const double ws2 = fmax((double)wc2[0], 0.0), ps2 = fmax((double)phic2[0], 0.0);
    const double ws3 = fmax((double)wc3[0], 0.0), ps3 = fmax((double)phic3[0], 0.0);

    for (int n = tid; n < 20; n += stride) {
        double wr = fmax((double)w0[n], 0.0) + ws0;
        g_P[4 * n]     = (float)(wr * I2PI);
        g_P[4 * n + 1] = (float)((fmax((double)phi0[n], 0.0) + ps0) * I2PI + 0.25);
        g_P[4 * n + 2] = A0[n];
        g_P[4 * n + 3] = 0.0f;
    }
    for (int k = tid; k < 25 * 20; k += stride) {   // k = m*20+n (source row-major)
        double wr = fmax((double)w1[k], 0.0) + ws1;
        g_P[80 + 2 * k]     = (float)(wr * I2PI);
        g_P[80 + 2 * k + 1] = (float)((fmax((double)phi1[k], 0.0) + ps1) * I2PI + 0.25);
    }
    for (int k = tid; k < 30 * 25; k += stride) {   // k = m*25+n
        double wr = fmax((double)w2[k], 0.0) + ws2;
        g_P[1080 + 2 * k]     = (float)(wr * I2PI);
        g_P[1080 + 2 * k + 1] = (float)((fmax((double)phi2[k], 0.0) + ps2) * I2PI + 0.25);
    }
    for (int k = tid; k < 30; k += stride) {
        double wr = fmax((double)w3[k], 0.0) + ws3;
        g_P[2580 + 2 * k]     = (float)(wr * I2PI);
        g_P[2580 + 2 * k + 1] = (float)((fmax((double)phi3[k], 0.0) + ps3) * I2PI + 0.25);
    }
}

// Kernel A: layers 0+1. Block = 256 threads = 4 INDEPENDENT waves (no
// barrier after the param staging), all covering the same 64 t-values.
// Each wave recomputes s0 in 20 registers (n unrolled, static indices)
// and owns an m-slice of layer 1 (7,6,6,6 of 25), writing s1[m][t] to
// global. 3125 blocks x 4 waves = 12512 balanced, uncoupled waves.
__launch_bounds__(256)
__global__ void k_l01()
{
    __shared__ float P[1080];   // L0 quads + L1 pairs
    for (int i = threadIdx.x; i < 1080; i += 256) P[i] = g_P[i];
    __syncthreads();            // the only barrier (param staging)

    const int l = threadIdx.x & 63;
    const int w = __builtin_amdgcn_readfirstlane(threadIdx.x >> 6);
    const int t = blockIdx.x * 64 + l;          // grid exact: 3125*64
    const float tv = fmaf((float)t, STEPF, 1.0f);

    // s0 in registers, n unrolled (static idx)
    float s0[20];
    float sum0 = 0.0f;
#pragma unroll
    for (int n = 0; n < 20; ++n) {
        const float ww = P[4 * n], ph = P[4 * n + 1], Aa = P[4 * n + 2];
        s0[n] = Aa * sinp(fmaf(ww, tv, ph));
        sum0 += s0[n];
    }

    // layer 1: wave's m-slice (rolled m, unrolled n)
    const int mS = w ? (1 + 6 * w) : 0;         // 0,7,13,19
    const int mC = w ? 6 : 7;
    for (int i = 0; i < mC; ++i) {
        const int m = mS + i;
        const float* __restrict__ pb = &P[80 + 40 * m];
        float acc = 0.0f;
#pragma unroll
        for (int n = 0; n < 20; ++n)
            acc = fmaf(sinp(fmaf(pb[2 * n], tv, pb[2 * n + 1])), s0[n], acc);
        g_s1[m * T_TOTAL + t] = fmaf(0.5f, acc, 0.5f * sum0);
    }
}

// Kernel B: layers 2+3 fused. Block = 256 threads = 4 waves over the same
// 64 t. Each wave loads s1[25] for its t into registers (coalesced; x4
// redundancy is L1-cache-hit), owns an m-slice of layer 2 (8,8,7,7 of 30),
// fuses layer 3 into a per-wave partial, and combines via 1 KB LDS + one
// end barrier. 12512 balanced waves, no mid-loop coupling.
__launch_bounds__(256)
__global__ void k_l23(float* __restrict__ out)
{
    __shared__ float P[1560];    // L2 pairs (1500) + L3 pairs (60)
    __shared__ float shp[4][64];

    const int l = threadIdx.x & 63;
    const int w = __builtin_amdgcn_readfirstlane(threadIdx.x >> 6);
    const int t = blockIdx.x * 64 + l;
    const float tv = fmaf((float)t, STEPF, 1.0f);

    for (int i = threadIdx.x; i < 1560; i += 256) P[i] = g_P[1080 + i];

    // s1 into registers (issue loads before the staging barrier)
    float s1v[25];
#pragma unroll
    for (int n = 0; n < 25; ++n) s1v[n] = g_s1[n * T_TOTAL + t];
    __syncthreads();

    float sum1 = 0.0f;
#pragma unroll
    for (int n = 0; n < 25; ++n) sum1 += s1v[n];

    const int mS = (w < 2) ? 8 * w : (16 + 7 * (w - 2));   // 0,8,16,23
    const int mC = (w < 2) ? 8 : 7;
    float pw = 0.0f;
    for (int i = 0; i < mC; ++i) {
        const int m = mS + i;
        const float* __restrict__ pb = &P[50 * m];
        float acc = 0.0f;
#pragma unroll
        for (int n = 0; n < 25; ++n)
            acc = fmaf(sinp(fmaf(pb[2 * n], tv, pb[2 * n + 1])), s1v[n], acc);
        const float s2 = fmaf(0.5f, acc, 0.5f * sum1);
        const float r3 = sinp(fmaf(P[1500 + 2 * m], tv, P[1501 + 2 * m]));
        pw = fmaf(fmaf(0.5f, r3, 0.5f), s2, pw);
    }
    shp[w][l] = pw;
    __syncthreads();
    if (w == 0)
        out[t] = (shp[0][l] + shp[1][l]) + (shp[2][l] + shp[3][l]);
}

extern "C" void kernel_launch(void* const* d_in, const int* in_sizes, int n_in,
                              void* d_out, int out_size, void* d_ws, size_t ws_size,
                              hipStream_t stream) {
    (void)in_sizes; (void)n_in; (void)d_ws; (void)ws_size; (void)out_size;
    const float* A0    = (const float*)d_in[1];
    const float* w0    = (const float*)d_in[2];
    const float* phi0  = (const float*)d_in[3];
    const float* wc0   = (const float*)d_in[4];
    const float* phic0 = (const float*)d_in[5];
    const float* w1    = (const float*)d_in[6];
    const float* phi1  = (const float*)d_in[7];
    const float* wc1   = (const float*)d_in[8];
    const float* phic1 = (const float*)d_in[9];
    const float* w2    = (const float*)d_in[10];
    const float* phi2  = (const float*)d_in[11];
    const float* wc2   = (const float*)d_in[12];
    const float* phic2 = (const float*)d_in[13];
    const float* w3    = (const float*)d_in[14];
    const float* phi3  = (const float*)d_in[15];
    const float* wc3   = (const float*)d_in[16];
    const float* phic3 = (const float*)d_in[17];

    float* out = (float*)d_out;

    hipLaunchKernelGGL(prep_kernel, dim3(6), dim3(256), 0, stream,
                       A0, w0, phi0, wc0, phic0,
                       w1, phi1, wc1, phic1,
                       w2, phi2, wc2, phic2,
                       w3, phi3, wc3, phic3);

    const int grid = T_TOTAL / 64;   // 3125, exact
    hipLaunchKernelGGL(k_l01, dim3(grid), dim3(256), 0, stream);
    hipLaunchKernelGGL(k_l23, dim3(grid), dim3(256), 0, stream, out);
}

// Round 13
// 62.534 us; speedup vs baseline: 1.0567x; 1.0567x over previous
//
#include <hip/hip_runtime.h>
#include <hip/hip_bf16.h>

#define T_TOTAL 200000
#define T_PAD   200192            // 782 * 256 (padded s1 rows; extra t unused)
#define STEPF   (999.0f / 199999.0f)

typedef float v4f __attribute__((ext_vector_type(4)));

// Parameter quads {ww', ph'+0.25, C=2cos(ww*64*step), extra}, phases in
// REVOLUTIONS so sin(theta) = cos(2*pi*(fract(rev)-0.5)) (even poly):
// L0: [4n]            n<20, extra = A0          [0,80)
// L1: [80  + 4*(m*20+n)] m<25, n<20             [80,2080)
// L2: [2080 + 4*(m*25+n)] m<30, n<25            [2080,5080)
// L3: [5080 + 4m]     m<30                      [5080,5200)
__device__ float g_P[5200];
// Inter-kernel s1[m][t] buffer (padded): 25 x 200192 = 20 MB.
__device__ float g_s1[25 * T_PAD];

// sin(2*pi*rev) via even poly: cos(2*pi*h), h = fract(rev)-0.5. |err| ~= 4e-5.
__device__ __forceinline__ float sinp(float rev) {
    float g = __builtin_amdgcn_fractf(rev);
    float h = g - 0.5f;
    float u = h * h;
    float p = fmaf(45.621248f, u, -82.391040f);
    p = fmaf(p, u, 64.671616f);
    p = fmaf(p, u, -19.730960f);
    p = fmaf(p, u, 0.9999618f);
    return p;
}

__global__ void prep_kernel(
    const float* __restrict__ A0,
    const float* __restrict__ w0, const float* __restrict__ phi0,
    const float* __restrict__ wc0, const float* __restrict__ phic0,
    const float* __restrict__ w1, const float* __restrict__ phi1,
    const float* __restrict__ wc1, const float* __restrict__ phic1,
    const float* __restrict__ w2, const float* __restrict__ phi2,
    const float* __restrict__ wc2, const float* __restrict__ phic2,
    const float* __restrict__ w3, const float* __restrict__ phi3,
    const float* __restrict__ wc3, const float* __restrict__ phic3)
{
    const int tid = blockIdx.x * blockDim.x + threadIdx.x;
    const int stride = blockDim.x * gridDim.x;

    const double I2PI = 0.15915494309189535;
    const double D64  = 64.0 * 999.0 / 199999.0;   // tv-step between j's

    const double ws0 = fmax((double)wc0[0], 0.0), ps0 = fmax((double)phic0[0], 0.0);
    const double ws1 = fmax((double)wc1[0], 0.0), ps1 = fmax((double)phic1[0], 0.0);
    const double ws2 = fmax((double)wc2[0], 0.0), ps2 = fmax((double)phic2[0], 0.0);
    const double ws3 = fmax((double)wc3[0], 0.0), ps3 = fmax((double)phic3[0], 0.0);

    for (int n = tid; n < 20; n += stride) {
        double wr = fmax((double)w0[n], 0.0) + ws0;
        g_P[4 * n]     = (float)(wr * I2PI);
        g_P[4 * n + 1] = (float)((fmax((double)phi0[n], 0.0) + ps0) * I2PI + 0.25);
        g_P[4 * n + 2] = (float)(2.0 * cos(wr * D64));
        g_P[4 * n + 3] = A0[n];
    }
    for (int k = tid; k < 25 * 20; k += stride) {   // k = m*20+n
        double wr = fmax((double)w1[k], 0.0) + ws1;
        g_P[80 + 4 * k]     = (float)(wr * I2PI);
        g_P[80 + 4 * k + 1] = (float)((fmax((double)phi1[k], 0.0) + ps1) * I2PI + 0.25);
        g_P[80 + 4 * k + 2] = (float)(2.0 * cos(wr * D64));
        g_P[80 + 4 * k + 3] = 0.0f;
    }
    for (int k = tid; k < 30 * 25; k += stride) {   // k = m*25+n
        double wr = fmax((double)w2[k], 0.0) + ws2;
        g_P[2080 + 4 * k]     = (float)(wr * I2PI);
        g_P[2080 + 4 * k + 1] = (float)((fmax((double)phi2[k], 0.0) + ps2) * I2PI + 0.25);
        g_P[2080 + 4 * k + 2] = (float)(2.0 * cos(wr * D64));
        g_P[2080 + 4 * k + 3] = 0.0f;
    }
    for (int m = tid; m < 30; m += stride) {
        double wr = fmax((double)w3[m], 0.0) + ws3;
        g_P[5080 + 4 * m]     = (float)(wr * I2PI);
        g_P[5080 + 4 * m + 1] = (float)((fmax((double)phi3[m], 0.0) + ps3) * I2PI + 0.25);
        g_P[5080 + 4 * m + 2] = (float)(2.0 * cos(wr * D64));
        g_P[5080 + 4 * m + 3] = 0.0f;
    }
}

// Kernel A: layers 0+1. 782 blocks x 4 waves cover 256 t each:
// t = tb + l + 64j, j<4 per thread (R=4: j=0,1 direct poly, j=2,3 via
// 1-fma Chebyshev recurrence x_{j+1} = C*x_j - x_{j-1}).
// s0 staged in LDS [n][j][lane] (one barrier); wave owns 7/6/6/6 m's.
// Per (m,n): one uniform ds_read_b128 {ww,ph,C} + 22 VALU for 4 sines.
__launch_bounds__(256)
__global__ void k_l01()
{
    __shared__ float P[2080];        // L0+L1 param quads (8320 B)
    __shared__ float s0s[20 * 256];  // s0[n][j][lane]   (20480 B)

    for (int i = threadIdx.x; i < 2080; i += 256) P[i] = g_P[i];

    const int l = threadIdx.x & 63;
    const int w = __builtin_amdgcn_readfirstlane(threadIdx.x >> 6);
    const int tb = blockIdx.x * 256;
    const float tv0 = fmaf((float)(tb + l), STEPF, 1.0f);
    const float tv1 = fmaf((float)(tb + l + 64), STEPF, 1.0f);

    // layer 0: wave w computes n = 5w..5w+4 (params direct from g_P: s_load,
    // overlaps the P staging; single barrier covers both)
#pragma unroll
    for (int i = 0; i < 5; ++i) {
        const int n = 5 * w + i;
        const v4f q = *(const v4f*)&g_P[4 * n];
        float x0 = q[3] * sinp(fmaf(q[0], tv0, q[1]));
        float x1 = q[3] * sinp(fmaf(q[0], tv1, q[1]));
        float x2 = fmaf(q[2], x1, -x0);
        float x3 = fmaf(q[2], x2, -x1);
        s0s[n * 256 +       l] = x0;
        s0s[n * 256 +  64 + l] = x1;
        s0s[n * 256 + 128 + l] = x2;
        s0s[n * 256 + 192 + l] = x3;
    }
    __syncthreads();

    float sum0[4] = {0.f, 0.f, 0.f, 0.f};
#pragma unroll
    for (int n = 0; n < 20; ++n) {
        sum0[0] += s0s[n * 256 +       l];
        sum0[1] += s0s[n * 256 +  64 + l];
        sum0[2] += s0s[n * 256 + 128 + l];
        sum0[3] += s0s[n * 256 + 192 + l];
    }

    const int mS = w ? (1 + 6 * w) : 0;          // 0,7,13,19
    const int mC = w ? 6 : 7;
    for (int i = 0; i < mC; ++i) {
        const int m = mS + i;
        float a0 = 0.f, a1 = 0.f, a2 = 0.f, a3 = 0.f;
        const float* __restrict__ pb = &P[80 + 80 * m];
#pragma unroll
        for (int n = 0; n < 20; ++n) {
            const v4f q = *(const v4f*)&pb[4 * n];      // uniform b128
            const float s00 = s0s[n * 256 +       l];
            const float s01 = s0s[n * 256 +  64 + l];
            const float s02 = s0s[n * 256 + 128 + l];
            const float s03 = s0s[n * 256 + 192 + l];
            float x0 = sinp(fmaf(q[0], tv0, q[1]));
            float x1 = sinp(fmaf(q[0], tv1, q[1]));
            float x2 = fmaf(q[2], x1, -x0);
            float x3 = fmaf(q[2], x2, -x1);
            a0 = fmaf(x0, s00, a0);
            a1 = fmaf(x1, s01, a1);
            a2 = fmaf(x2, s02, a2);
            a3 = fmaf(x3, s03, a3);
        }
        float* __restrict__ o = &g_s1[m * T_PAD + tb];
        o[l]       = fmaf(0.5f, a0, 0.5f * sum0[0]);
        o[64 + l]  = fmaf(0.5f, a1, 0.5f * sum0[1]);
        o[128 + l] = fmaf(0.5f, a2, 0.5f * sum0[2]);
        o[192 + l] = fmaf(0.5f, a3, 0.5f * sum0[3]);
    }
}

// Kernel B: layers 2+3 fused. Same 256-t block shape; s1 tile + params
// staged to LDS (one barrier); wave owns 8/8/7/7 m's; L3 folded per-m;
// 4-wave partial reduce via 4 KB LDS + one end barrier.
__launch_bounds__(256)
__global__ void k_l23(float* __restrict__ out)
{
    __shared__ float P[3120];        // L2+L3 quads (12480 B)
    __shared__ float s1s[25 * 256];  // s1[n][j][lane] (25600 B)
    __shared__ float shp[16 * 64];   // partials [w][j][lane] (4096 B)

    const int tb = blockIdx.x * 256;
    for (int i = threadIdx.x; i < 3120; i += 256) P[i] = g_P[2080 + i];
    for (int i = threadIdx.x; i < 25 * 256; i += 256) {
        const int n = i >> 8;
        s1s[i] = g_s1[n * T_PAD + tb + (i & 255)];   // coalesced per row
    }
    __syncthreads();

    const int l = threadIdx.x & 63;
    const int w = __builtin_amdgcn_readfirstlane(threadIdx.x >> 6);
    const float tv0 = fmaf((float)(tb + l), STEPF, 1.0f);
    const float tv1 = fmaf((float)(tb + l + 64), STEPF, 1.0f);

    float sum1[4] = {0.f, 0.f, 0.f, 0.f};
#pragma unroll
    for (int n = 0; n < 25; ++n) {
        sum1[0] += s1s[n * 256 +       l];
        sum1[1] += s1s[n * 256 +  64 + l];
        sum1[2] += s1s[n * 256 + 128 + l];
        sum1[3] += s1s[n * 256 + 192 + l];
    }

    const int mS = (w < 2) ? 8 * w : (16 + 7 * (w - 2));   // 0,8,16,23
    const int mC = (w < 2) ? 8 : 7;
    float p0 = 0.f, p1 = 0.f, p2 = 0.f, p3 = 0.f;
    for (int i = 0; i < mC; ++i) {
        const int m = mS + i;
        float a0 = 0.f, a1 = 0.f, a2 = 0.f, a3 = 0.f;
        const float* __restrict__ pb = &P[100 * m];
#pragma unroll
        for (int n = 0; n < 25; ++n) {
            const v4f q = *(const v4f*)&pb[4 * n];      // uniform b128
            const float s10 = s1s[n * 256 +       l];
            const float s11 = s1s[n * 256 +  64 + l];
            const float s12 = s1s[n * 256 + 128 + l];
            const float s13 = s1s[n * 256 + 192 + l];
            float x0 = sinp(fmaf(q[0], tv0, q[1]));
            float x1 = sinp(fmaf(q[0], tv1, q[1]));
            float x2 = fmaf(q[2], x1, -x0);
            float x3 = fmaf(q[2], x2, -x1);
            a0 = fmaf(x0, s10, a0);
            a1 = fmaf(x1, s11, a1);
            a2 = fmaf(x2, s12, a2);
            a3 = fmaf(x3, s13, a3);
        }
        // layer 3 term for this m (Chebyshev over j as well)
        const v4f q3 = *(const v4f*)&P[3000 + 4 * m];
        float y0 = sinp(fmaf(q3[0], tv0, q3[1]));
        float y1 = sinp(fmaf(q3[0], tv1, q3[1]));
        float y2 = fmaf(q3[2], y1, -y0);
        float y3 = fmaf(q3[2], y2, -y1);
        p0 = fmaf(fmaf(0.5f, y0, 0.5f), fmaf(0.5f, a0, 0.5f * sum1[0]), p0);
        p1 = fmaf(fmaf(0.5f, y1, 0.5f), fmaf(0.5f, a1, 0.5f * sum1[1]), p1);
        p2 = fmaf(fmaf(0.5f, y2, 0.5f), fmaf(0.5f, a2, 0.5f * sum1[2]), p2);
        p3 = fmaf(fmaf(0.5f, y3, 0.5f), fmaf(0.5f, a3, 0.5f * sum1[3]), p3);
    }
    shp[(w * 4 + 0) * 64 + l] = p0;
    shp[(w * 4 + 1) * 64 + l] = p1;
    shp[(w * 4 + 2) * 64 + l] = p2;
    shp[(w * 4 + 3) * 64 + l] = p3;
    __syncthreads();

    // wave w handles j == w (exactly 4 waves)
    const float r = (shp[(0 * 4 + w) * 64 + l] + shp[(1 * 4 + w) * 64 + l])
                  + (shp[(2 * 4 + w) * 64 + l] + shp[(3 * 4 + w) * 64 + l]);
    const int tt = tb + 64 * w + l;
    if (tt < T_TOTAL) out[tt] = r;
}

extern "C" void kernel_launch(void* const* d_in, const int* in_sizes, int n_in,
                              void* d_out, int out_size, void* d_ws, size_t ws_size,
                              hipStream_t stream) {
    (void)in_sizes; (void)n_in; (void)d_ws; (void)ws_size; (void)out_size;
    const float* A0    = (const float*)d_in[1];
    const float* w0    = (const float*)d_in[2];
    const float* phi0  = (const float*)d_in[3];
    const float* wc0   = (const float*)d_in[4];
    const float* phic0 = (const float*)d_in[5];
    const float* w1    = (const float*)d_in[6];
    const float* phi1  = (const float*)d_in[7];
    const float* wc1   = (const float*)d_in[8];
    const float* phic1 = (const float*)d_in[9];
    const float* w2    = (const float*)d_in[10];
    const float* phi2  = (const float*)d_in[11];
    const float* wc2   = (const float*)d_in[12];
    const float* phic2 = (const float*)d_in[13];
    const float* w3    = (const float*)d_in[14];
    const float* phi3  = (const float*)d_in[15];
    const float* wc3   = (const float*)d_in[16];
    const float* phic3 = (const float*)d_in[17];

    float* out = (float*)d_out;

    hipLaunchKernelGGL(prep_kernel, dim3(6), dim3(256), 0, stream,
                       A0, w0, phi0, wc0, phic0,
                       w1, phi1, wc1, phic1,
                       w2, phi2, wc2, phic2,
                       w3, phi3, wc3, phic3);

    const int grid = (T_TOTAL + 255) / 256;   // 782
    hipLaunchKernelGGL(k_l01, dim3(grid), dim3(256), 0, stream);
    hipLaunchKernelGGL(k_l23, dim3(grid), dim3(256), 0, stream, out);
}